// Round 9
// baseline (249.725 us; speedup 1.0000x reference)
//
#include <hip/hip_runtime.h>
#include <hip/hip_bf16.h>

#define NROW 131072   // B*L
#define D 256
#define K 320
#define BN_EPS 1e-5f
#define FIXSCALE 16777216.0f   // 2^24 fixed-point for deterministic atomics
#define XSH 264       // halfs per LDS row: 256 + 8 pad

typedef _Float16 half8 __attribute__((ext_vector_type(8)));
typedef float f32x4 __attribute__((ext_vector_type(4)));

// ws layout:
//   u64 acc[512]        @ 0       (4 KB)
//   f32 meanb[256]      @ 4096
//   f32 rsb[256]        @ 5120
//   f32 cnorm[320]      @ 6144
//   f16 cbx             @ 8192    (320 KB) codebook hi/lo, per-ks chunked:
//     chunk layout: [ks][c][lane][8]  c=0..39 (0-19 hi tiles, 20-39 lo tiles)
//     byte addr = ((ks*40 + c)*64 + lane)*16

// ---------------- kernel 0: zero the fixed-point accumulators ---------------
__global__ __launch_bounds__(256) void k_zero(unsigned long long* __restrict__ acc) {
  acc[threadIdx.x] = 0ull;
  acc[256 + threadIdx.x] = 0ull;
}

// ---------------- kernel 1: per-block channel partials -> fixed-point atomics
__global__ __launch_bounds__(256) void k_stats_partial(const float* __restrict__ x,
                                                       unsigned long long* __restrict__ acc) {
  const int d = threadIdx.x;
  const int blk = blockIdx.x;         // 512 blocks, 256 rows each
  const float* p = x + (size_t)blk * 256 * D + d;
  float s = 0.f, q = 0.f;
  #pragma unroll 4
  for (int r = 0; r < 256; ++r) {
    float v = p[(size_t)r * D];
    s += v;
    q = fmaf(v, v, q);
  }
  long long si = llrintf(s * FIXSCALE);
  long long qi = llrintf(q * FIXSCALE);
  atomicAdd(&acc[d],       (unsigned long long)si);
  atomicAdd(&acc[256 + d], (unsigned long long)qi);
}

// ---------------- kernel 2: finalize stats + codebook norms -----------------
__global__ __launch_bounds__(256) void k_stats_final(const unsigned long long* __restrict__ acc,
                                                     const float* __restrict__ cb,
                                                     float* __restrict__ meanb,
                                                     float* __restrict__ rsb,
                                                     float* __restrict__ cnorm) {
  const int t = threadIdx.x;
  if (blockIdx.x == 0) {
    double s = (double)(long long)acc[t]       / (double)FIXSCALE;
    double q = (double)(long long)acc[256 + t] / (double)FIXSCALE;
    double mean = s / (double)NROW;
    double var  = q / (double)NROW - mean * mean;
    meanb[t] = (float)mean;
    rsb[t]   = (float)(1.0 / sqrt(var + (double)BN_EPS));
  } else {
    for (int code = t; code < K; code += 256) {
      const float* c = cb + (size_t)code * D;
      float s = 0.f;
      for (int dd = 0; dd < D; ++dd) s = fmaf(c[dd], c[dd], s);
      cnorm[code] = s;
    }
  }
}

// ---------------- kernel 2b: split codebook to fp16 hi/lo, per-ks chunks ----
// MFMA B-fragment: lane l holds code = nt*16 + (l&15), k = ks*32 + (l>>4)*8..+8
// Stored at ((ks*40 + nt)*64 + l)*8 (hi) and ((ks*40 + 20 + nt)*64 + l)*8 (lo)
__global__ __launch_bounds__(64) void k_cbprep(const float* __restrict__ cb,
                                               _Float16* __restrict__ cbx) {
  const int nt = blockIdx.x;   // 0..19
  const int ks = blockIdx.y;   // 0..7
  const int l  = threadIdx.x;  // 0..63
  const int code = nt * 16 + (l & 15);
  const int d0 = ks * 32 + (l >> 4) * 8;
  const float* src = cb + (size_t)code * D + d0;
  const size_t bh = ((size_t)(ks * 40 + nt) * 64 + l) * 8;
  const size_t bl = ((size_t)(ks * 40 + 20 + nt) * 64 + l) * 8;
  #pragma unroll
  for (int j = 0; j < 8; ++j) {
    float v = src[j];
    _Float16 h = (_Float16)v;
    _Float16 lo = (_Float16)(v - (float)h);
    cbx[bh + j] = h;
    cbx[bl + j] = lo;
  }
}

// ---------------- kernel 3: normalize + MFMA distances + argmin + gather ----
// 1 block/CU (154 KB LDS), 8 waves. B staged cooperatively into LDS, double-
// buffered per 32-dim K-step; loads issued early, written late (T14).
__global__ __launch_bounds__(512)
__attribute__((amdgpu_waves_per_eu(2, 2)))
void k_main(const float* __restrict__ x,
            const float* __restrict__ w,
            const float* __restrict__ bias,
            const float* __restrict__ cb,
            const float* __restrict__ meanb,
            const float* __restrict__ rsb,
            const float* __restrict__ cnorm,
            const _Float16* __restrict__ cbx,
            float* __restrict__ out) {
  __shared__ _Float16 xh[64 * XSH];     // 33,792 B
  __shared__ _Float16 xl[64 * XSH];     // 33,792 B
  __shared__ _Float16 Bbuf[2 * 20480];  // 81,920 B (2 x 40 KB: 40 chunks of 1 KB)
  __shared__ float sxp[64 * 8];
  __shared__ float sx[64];
  __shared__ float redv[4 * 64];
  __shared__ int   redi[4 * 64];
  __shared__ int   bsel[64];

  const int t = threadIdx.x;
  const int row0 = (int)blockIdx.x * 64;
  const int lane = t & 63;
  const int wv = t >> 6;              // wave 0..7
  const int cgrp = wv & 3;            // code group: codes [cgrp*80, +80)
  const int rhalf = wv >> 2;          // row half
  const int c15 = lane & 15;
  const int g = lane >> 4;

  // staging macros: wave wv stages chunks {wv, 8+wv, 16+wv, 24+wv, 32+wv}
  float4 s0, s1, s2, s3, s4;
  const char* bsrc0 = (const char*)cbx + (size_t)wv * 1024 + (size_t)lane * 16;
#define ISSUE(ks1) {                                                     \
    const char* bs = bsrc0 + (size_t)(ks1) * 40960;                      \
    s0 = *(const float4*)(bs);                                           \
    s1 = *(const float4*)(bs + 8 * 1024);                                \
    s2 = *(const float4*)(bs + 16 * 1024);                               \
    s3 = *(const float4*)(bs + 24 * 1024);                               \
    s4 = *(const float4*)(bs + 32 * 1024);                               \
  }
#define WRITE(buf1) {                                                    \
    _Float16* bd = Bbuf + (buf1) * 20480 + wv * 512 + lane * 8;          \
    *(float4*)(bd)            = s0;                                      \
    *(float4*)(bd + 8 * 512)  = s1;                                      \
    *(float4*)(bd + 16 * 512) = s2;                                      \
    *(float4*)(bd + 24 * 512) = s3;                                      \
    *(float4*)(bd + 32 * 512) = s4;                                      \
  }

  ISSUE(0);                           // ks=0 B loads fly during x-staging

  // ---- stage normalized xb tile as fp16 hi/lo + per-row sum-sq partials ----
  {
    const int lr = t >> 3;            // local row 0..63
    const int oct = t & 7;            // 32-dim slice
    const int d0 = oct * 32;
    const float* xp = x + (size_t)(row0 + lr) * D + d0;
    float accq = 0.f;
    half8 hb, lb;
    _Float16* xhb = xh + lr * XSH;
    _Float16* xlb = xl + lr * XSH;
    #pragma unroll
    for (int e = 0; e < 8; ++e) {
      float4 xv = *(const float4*)(xp + e * 4);
      float4 mv = *(const float4*)(meanb + d0 + e * 4);
      float4 rv = *(const float4*)(rsb + d0 + e * 4);
      float4 wv4 = *(const float4*)(w + d0 + e * 4);
      float4 bv4 = *(const float4*)(bias + d0 + e * 4);
      float4 o;
      o.x = ((xv.x - mv.x) * rv.x) * wv4.x + bv4.x;
      o.y = ((xv.y - mv.y) * rv.y) * wv4.y + bv4.y;
      o.z = ((xv.z - mv.z) * rv.z) * wv4.z + bv4.z;
      o.w = ((xv.w - mv.w) * rv.w) * wv4.w + bv4.w;
      accq = fmaf(o.x, o.x, accq);
      accq = fmaf(o.y, o.y, accq);
      accq = fmaf(o.z, o.z, accq);
      accq = fmaf(o.w, o.w, accq);
      const int sl = (e & 1) * 4;
      hb[sl + 0] = (_Float16)o.x;  lb[sl + 0] = (_Float16)(o.x - (float)hb[sl + 0]);
      hb[sl + 1] = (_Float16)o.y;  lb[sl + 1] = (_Float16)(o.y - (float)hb[sl + 1]);
      hb[sl + 2] = (_Float16)o.z;  lb[sl + 2] = (_Float16)(o.z - (float)hb[sl + 2]);
      hb[sl + 3] = (_Float16)o.w;  lb[sl + 3] = (_Float16)(o.w - (float)hb[sl + 3]);
      if (e & 1) {
        const int c = oct * 4 + (e >> 1);       // 16B chunk index 0..31
        *(half8*)(xhb + c * 8) = hb;
        *(half8*)(xlb + c * 8) = lb;
      }
    }
    sxp[lr * 8 + oct] = accq;
  }
  __syncthreads();
  WRITE(0);                           // land ks=0 B chunk into buf0
  if (t < 64) {
    float s = 0.f;
    #pragma unroll
    for (int j = 0; j < 8; ++j) s += sxp[t * 8 + j];
    sx[t] = s;
  }
  __syncthreads();                    // buf0 + sx visible

  // ---- MFMA k-loop: 2-phase double-buffered B, one barrier per K-step ----
  f32x4 acc[2][5];
  #pragma unroll
  for (int i = 0; i < 2; ++i)
    #pragma unroll
    for (int tt = 0; tt < 5; ++tt) acc[i][tt] = (f32x4){0.f, 0.f, 0.f, 0.f};

  #pragma unroll
  for (int ks = 0; ks < 8; ++ks) {
    if (ks < 7) ISSUE(ks + 1);        // issue-early: next K-step B loads

    const _Float16* bb = Bbuf + (ks & 1) * 20480 + cgrp * 5 * 512 + lane * 8;
    half8 bh[5], bl[5];
    #pragma unroll
    for (int tt = 0; tt < 5; ++tt) {
      bh[tt] = *(const half8*)(bb + tt * 512);
      bl[tt] = *(const half8*)(bb + tt * 512 + 20 * 512);
    }
    half8 ah[2], al[2];
    #pragma unroll
    for (int i = 0; i < 2; ++i) {
      const int row = (rhalf * 2 + i) * 16 + c15;
      ah[i] = *(const half8*)(xh + row * XSH + (ks * 4 + g) * 8);
      al[i] = *(const half8*)(xl + row * XSH + (ks * 4 + g) * 8);
    }
    #pragma unroll
    for (int tt = 0; tt < 5; ++tt) {
      #pragma unroll
      for (int i = 0; i < 2; ++i) {
        acc[i][tt] = __builtin_amdgcn_mfma_f32_16x16x32_f16(ah[i], bh[tt], acc[i][tt], 0, 0, 0);
        acc[i][tt] = __builtin_amdgcn_mfma_f32_16x16x32_f16(ah[i], bl[tt], acc[i][tt], 0, 0, 0);
        acc[i][tt] = __builtin_amdgcn_mfma_f32_16x16x32_f16(al[i], bh[tt], acc[i][tt], 0, 0, 0);
      }
    }

    if (ks < 7) WRITE((ks + 1) & 1);  // write-late into the other buffer
    __syncthreads();
  }

  // ---- epilogue constants ----
  float cnreg[5];
  #pragma unroll
  for (int tt = 0; tt < 5; ++tt) cnreg[tt] = cnorm[cgrp * 80 + tt * 16 + c15];
  float sxr[2][4];
  #pragma unroll
  for (int i = 0; i < 2; ++i)
    #pragma unroll
    for (int r = 0; r < 4; ++r) sxr[i][r] = sx[(rhalf * 2 + i) * 16 + g * 4 + r];

  // ---- d2 + running lexicographic argmin (C/D: col=lane&15, row=(lane>>4)*4+r)
  float bv[2][4];
  int   bix[2][4];
  #pragma unroll
  for (int i = 0; i < 2; ++i)
    #pragma unroll
    for (int r = 0; r < 4; ++r) { bv[i][r] = 3.4e38f; bix[i][r] = 0x7fffffff; }

  #pragma unroll
  for (int i = 0; i < 2; ++i)
    #pragma unroll
    for (int tt = 0; tt < 5; ++tt) {
      const int code = cgrp * 80 + tt * 16 + c15;
      #pragma unroll
      for (int r = 0; r < 4; ++r) {
        const float d2 = (sxr[i][r] - 2.0f * acc[i][tt][r]) + cnreg[tt];
        if (d2 < bv[i][r] || (d2 == bv[i][r] && code < bix[i][r])) {
          bv[i][r] = d2; bix[i][r] = code;
        }
      }
    }

  // butterfly reduce across the 16 lanes holding the same rows
  #pragma unroll
  for (int off = 8; off >= 1; off >>= 1) {
    #pragma unroll
    for (int i = 0; i < 2; ++i)
      #pragma unroll
      for (int r = 0; r < 4; ++r) {
        const float ov = __shfl_xor(bv[i][r], off);
        const int   oi = __shfl_xor(bix[i][r], off);
        if (ov < bv[i][r] || (ov == bv[i][r] && oi < bix[i][r])) {
          bv[i][r] = ov; bix[i][r] = oi;
        }
      }
  }
  if (c15 == 0) {
    #pragma unroll
    for (int i = 0; i < 2; ++i)
      #pragma unroll
      for (int r = 0; r < 4; ++r) {
        const int row = (rhalf * 2 + i) * 16 + g * 4 + r;
        redv[cgrp * 64 + row] = bv[i][r];
        redi[cgrp * 64 + row] = bix[i][r];
      }
  }
  __syncthreads();

  // combine 4 code-groups (disjoint ascending ranges -> strict < keeps lowest)
  if (t < 64) {
    float fv = redv[t];
    int   fi = redi[t];
    #pragma unroll
    for (int w2 = 1; w2 < 4; ++w2) {
      const float v2 = redv[w2 * 64 + t];
      const int   i2 = redi[w2 * 64 + t];
      if (v2 < fv) { fv = v2; fi = i2; }
    }
    bsel[t] = fi;
    out[(size_t)NROW * D + row0 + t] = (float)fi;
  }
  __syncthreads();

  // ---- gather chosen codes (exact f32 copy), 128B segments per 8 lanes ----
  {
    const int lr = t >> 3;
    const int f4i = t & 7;
    const int code = bsel[lr];
    const float* cp = cb + (size_t)code * D;
    float* op = out + (size_t)(row0 + lr) * D;
    #pragma unroll
    for (int e = 0; e < 8; ++e) {
      *(float4*)(op + (f4i + 8 * e) * 4) = *(const float4*)(cp + (f4i + 8 * e) * 4);
    }
  }
#undef ISSUE
#undef WRITE
}

extern "C" void kernel_launch(void* const* d_in, const int* in_sizes, int n_in,
                              void* d_out, int out_size, void* d_ws, size_t ws_size,
                              hipStream_t stream) {
  const float* x    = (const float*)d_in[0];
  const float* w    = (const float*)d_in[1];
  const float* bias = (const float*)d_in[2];
  const float* cb   = (const float*)d_in[3];
  float* out = (float*)d_out;

  unsigned long long* acc = (unsigned long long*)d_ws;
  float* meanb = (float*)((char*)d_ws + 4096);
  float* rsb   = meanb + 256;
  float* cnorm = rsb + 256;
  _Float16* cbx = (_Float16*)((char*)d_ws + 8192);   // 320 KB

  k_zero<<<1, 256, 0, stream>>>(acc);
  k_cbprep<<<dim3(20, 8), 64, 0, stream>>>(cb, cbx);
  k_stats_partial<<<512, 256, 0, stream>>>(x, acc);
  k_stats_final<<<2, 256, 0, stream>>>(acc, cb, meanb, rsb, cnorm);
  k_main<<<NROW / 64, 512, 0, stream>>>(x, w, bias, cb, meanb, rsb, cnorm, cbx, out);
}

// Round 11
// 154.170 us; speedup vs baseline: 1.6198x; 1.6198x over previous
//
#include <hip/hip_runtime.h>
#include <hip/hip_bf16.h>

#define NROW 131072   // B*L
#define D 256
#define K 320
#define BN_EPS 1e-5f
#define FIXSCALE 16777216.0f   // 2^24 fixed-point for deterministic atomics

typedef _Float16 half8 __attribute__((ext_vector_type(8)));
typedef float f32x4 __attribute__((ext_vector_type(4)));

// ws layout:
//   u64 acc[512]   @ 0      (4 KB)
//   f32 meanb[256] @ 4096
//   f32 rsb[256]   @ 5120
//   f32 cnorm[320] @ 6144
//   f16 cbx        @ 8192   (320 KB) codebook fragments, chunk-contiguous:
//     tile nt(0..19), hl(0=hi,1=lo), ks(0..7): halfs at ((nt*2+hl)*8+ks)*512 + lane*8
//     -> chunk c (tiles 2c,2c+1) is the contiguous 32 KB at c*32768 bytes

// ---------------- kernel 0: zero the fixed-point accumulators ---------------
__global__ __launch_bounds__(256) void k_zero(unsigned long long* __restrict__ acc) {
  acc[threadIdx.x] = 0ull;
  acc[256 + threadIdx.x] = 0ull;
}

// ---------------- kernel 1: per-block channel partials -> fixed-point atomics
__global__ __launch_bounds__(256) void k_stats_partial(const float* __restrict__ x,
                                                       unsigned long long* __restrict__ acc) {
  const int d = threadIdx.x;
  const int blk = blockIdx.x;         // 512 blocks, 256 rows each
  const float* p = x + (size_t)blk * 256 * D + d;
  float s = 0.f, q = 0.f;
  #pragma unroll 4
  for (int r = 0; r < 256; ++r) {
    float v = p[(size_t)r * D];
    s += v;
    q = fmaf(v, v, q);
  }
  long long si = llrintf(s * FIXSCALE);
  long long qi = llrintf(q * FIXSCALE);
  atomicAdd(&acc[d],       (unsigned long long)si);
  atomicAdd(&acc[256 + d], (unsigned long long)qi);
}

// ---------------- kernel 2: finalize stats + codebook norms -----------------
__global__ __launch_bounds__(256) void k_stats_final(const unsigned long long* __restrict__ acc,
                                                     const float* __restrict__ cb,
                                                     float* __restrict__ meanb,
                                                     float* __restrict__ rsb,
                                                     float* __restrict__ cnorm) {
  const int t = threadIdx.x;
  if (blockIdx.x == 0) {
    double s = (double)(long long)acc[t]       / (double)FIXSCALE;
    double q = (double)(long long)acc[256 + t] / (double)FIXSCALE;
    double mean = s / (double)NROW;
    double var  = q / (double)NROW - mean * mean;
    meanb[t] = (float)mean;
    rsb[t]   = (float)(1.0 / sqrt(var + (double)BN_EPS));
  } else {
    for (int code = t; code < K; code += 256) {
      const float* c = cb + (size_t)code * D;
      float s = 0.f;
      for (int dd = 0; dd < D; ++dd) s = fmaf(c[dd], c[dd], s);
      cnorm[code] = s;
    }
  }
}

// ---------------- kernel 2b: split codebook to fp16 hi/lo fragments ---------
// MFMA B-fragment: lane l holds code = nt*16 + (l&15), k = ks*32 + (l>>4)*8..+8
__global__ __launch_bounds__(64) void k_cbprep(const float* __restrict__ cb,
                                               _Float16* __restrict__ cbx) {
  const int nt = blockIdx.x;   // 0..19
  const int ks = blockIdx.y;   // 0..7
  const int l  = threadIdx.x;  // 0..63
  const int code = nt * 16 + (l & 15);
  const int d0 = ks * 32 + (l >> 4) * 8;
  const float* src = cb + (size_t)code * D + d0;
  const size_t bh = ((size_t)(nt * 2 + 0) * 8 + ks) * 512 + l * 8;
  const size_t bl = ((size_t)(nt * 2 + 1) * 8 + ks) * 512 + l * 8;
  #pragma unroll
  for (int j = 0; j < 8; ++j) {
    float v = src[j];
    _Float16 h = (_Float16)v;
    _Float16 lo = (_Float16)(v - (float)h);
    cbx[bh + j] = h;
    cbx[bl + j] = lo;
  }
}

// ---------------- kernel 3: A-in-registers, B chunks via LDS dbuf -----------
// 1024 blocks x 512 thr. Wave wv owns rows row0 + wv*16 .. +16 against ALL
// 320 codes; A fragments (8 ks x hi/lo) live in 64 VGPRs the whole kernel.
__global__ __launch_bounds__(512, 4) void k_main(const float* __restrict__ x,
                                                 const float* __restrict__ w,
                                                 const float* __restrict__ bias,
                                                 const float* __restrict__ cb,
                                                 const float* __restrict__ meanb,
                                                 const float* __restrict__ rsb,
                                                 const float* __restrict__ cnorm,
                                                 const _Float16* __restrict__ cbx,
                                                 float* __restrict__ out) {
  __shared__ _Float16 Bbuf[2][16384];   // 2 x 32 KB code-chunks
  __shared__ float sxs[128];            // per-row sum of squares of normalized x
  __shared__ int bsel[128];

  const int t = threadIdx.x;
  const int lane = t & 63;
  const int wv = t >> 6;              // wave 0..7
  const int c15 = lane & 15;
  const int g = lane >> 4;
  const int row0 = (int)blockIdx.x * 128;

  // ---- cooperative B staging: chunk c = 32 KB contiguous, reg-staged ----
  float4 s0, s1, s2, s3;
  const char* stg_src = (const char*)cbx + (size_t)t * 16;
#define ISSUE(c) {                                                  \
    const char* p_ = stg_src + (size_t)(c) * 32768;                 \
    s0 = *(const float4*)(p_);                                      \
    s1 = *(const float4*)(p_ + 8192);                               \
    s2 = *(const float4*)(p_ + 16384);                              \
    s3 = *(const float4*)(p_ + 24576);                              \
  }
#define WRITE(b) {                                                  \
    char* q_ = (char*)Bbuf[b] + t * 16;                             \
    *(float4*)(q_)         = s0;                                    \
    *(float4*)(q_ + 8192)  = s1;                                    \
    *(float4*)(q_ + 16384) = s2;                                    \
    *(float4*)(q_ + 24576) = s3;                                    \
  }

  ISSUE(0);

  // ---- x -> A fragments in registers (normalize + fp16 hi/lo split) ----
  // lane l: row = row0 + wv*16 + (l&15), k-elems (l>>4)*8 + ks*32 .. +8
  half8 ah[8], al[8];
  float accq = 0.f;                   // per-lane partial sum of o^2 (64 dims)
  {
    const int arow = row0 + wv * 16 + c15;
    const int dbase = g * 8;
    const float* xp = x + (size_t)arow * D + dbase;
    #pragma unroll
    for (int ks = 0; ks < 8; ++ks) {
      const int d0 = dbase + ks * 32;
      float4 xa = *(const float4*)(xp + ks * 32);
      float4 xb2 = *(const float4*)(xp + ks * 32 + 4);
      float4 m0 = *(const float4*)(meanb + d0);
      float4 m1 = *(const float4*)(meanb + d0 + 4);
      float4 r0 = *(const float4*)(rsb + d0);
      float4 r1 = *(const float4*)(rsb + d0 + 4);
      float4 w0 = *(const float4*)(w + d0);
      float4 w1 = *(const float4*)(w + d0 + 4);
      float4 b0 = *(const float4*)(bias + d0);
      float4 b1 = *(const float4*)(bias + d0 + 4);
      float o0 = ((xa.x - m0.x) * r0.x) * w0.x + b0.x;
      float o1 = ((xa.y - m0.y) * r0.y) * w0.y + b0.y;
      float o2 = ((xa.z - m0.z) * r0.z) * w0.z + b0.z;
      float o3 = ((xa.w - m0.w) * r0.w) * w0.w + b0.w;
      float o4 = ((xb2.x - m1.x) * r1.x) * w1.x + b1.x;
      float o5 = ((xb2.y - m1.y) * r1.y) * w1.y + b1.y;
      float o6 = ((xb2.z - m1.z) * r1.z) * w1.z + b1.z;
      float o7 = ((xb2.w - m1.w) * r1.w) * w1.w + b1.w;
      accq = fmaf(o0, o0, accq);
      accq = fmaf(o1, o1, accq);
      accq = fmaf(o2, o2, accq);
      accq = fmaf(o3, o3, accq);
      accq = fmaf(o4, o4, accq);
      accq = fmaf(o5, o5, accq);
      accq = fmaf(o6, o6, accq);
      accq = fmaf(o7, o7, accq);
      _Float16 h;
      h = (_Float16)o0; ah[ks][0] = h; al[ks][0] = (_Float16)(o0 - (float)h);
      h = (_Float16)o1; ah[ks][1] = h; al[ks][1] = (_Float16)(o1 - (float)h);
      h = (_Float16)o2; ah[ks][2] = h; al[ks][2] = (_Float16)(o2 - (float)h);
      h = (_Float16)o3; ah[ks][3] = h; al[ks][3] = (_Float16)(o3 - (float)h);
      h = (_Float16)o4; ah[ks][4] = h; al[ks][4] = (_Float16)(o4 - (float)h);
      h = (_Float16)o5; ah[ks][5] = h; al[ks][5] = (_Float16)(o5 - (float)h);
      h = (_Float16)o6; ah[ks][6] = h; al[ks][6] = (_Float16)(o6 - (float)h);
      h = (_Float16)o7; ah[ks][7] = h; al[ks][7] = (_Float16)(o7 - (float)h);
    }
  }
  // row sum: butterfly over the 4 k-slices (lanes xor 16, 32) — same order on
  // every lane of the row -> deterministic, lane-consistent f32 value.
  {
    float v1 = accq + __shfl_xor(accq, 16);
    float sxrow = v1 + __shfl_xor(v1, 32);
    if (lane < 16) sxs[wv * 16 + lane] = sxrow;
  }

  WRITE(0);                           // land chunk 0
  ISSUE(1);                           // chunk 1 in flight over chunk-0 compute
  __syncthreads();                    // buf0 + sxs visible

  // ---- chunk loop: 10 x (32 codes); argmin folded per chunk ----
  float bv[4];
  int   bix[4];
  #pragma unroll
  for (int r = 0; r < 4; ++r) { bv[r] = 3.4e38f; bix[r] = 0x7fffffff; }

  float sxr[4];
  #pragma unroll
  for (int r = 0; r < 4; ++r) sxr[r] = sxs[wv * 16 + g * 4 + r];

  for (int c = 0; c < 10; ++c) {
    const _Float16* bb = Bbuf[c & 1] + lane * 8;
    f32x4 acc[2];
    #pragma unroll
    for (int tt = 0; tt < 2; ++tt) {
      acc[tt] = (f32x4){0.f, 0.f, 0.f, 0.f};
      #pragma unroll
      for (int ks = 0; ks < 8; ++ks) {
        half8 bh = *(const half8*)(bb + ((tt * 2 + 0) * 8 + ks) * 512);
        half8 bl = *(const half8*)(bb + ((tt * 2 + 1) * 8 + ks) * 512);
        acc[tt] = __builtin_amdgcn_mfma_f32_16x16x32_f16(ah[ks], bh, acc[tt], 0, 0, 0);
        acc[tt] = __builtin_amdgcn_mfma_f32_16x16x32_f16(ah[ks], bl, acc[tt], 0, 0, 0);
        acc[tt] = __builtin_amdgcn_mfma_f32_16x16x32_f16(al[ks], bh, acc[tt], 0, 0, 0);
      }
    }
    // d2 = (sx - 2*dot) + cn  -- EXACT round-4..9 expression (rounding-matched
    // to the reference formula; see round-10 post-mortem)
    // C/D layout: col = lane&15 (code), row = (lane>>4)*4 + r
    #pragma unroll
    for (int tt = 0; tt < 2; ++tt) {
      const int code = c * 32 + tt * 16 + c15;
      const float cn = cnorm[code];
      #pragma unroll
      for (int r = 0; r < 4; ++r) {
        const float d2 = (sxr[r] - 2.0f * acc[tt][r]) + cn;
        if (d2 < bv[r] || (d2 == bv[r] && code < bix[r])) { bv[r] = d2; bix[r] = code; }
      }
    }
    if (c < 9) {
      WRITE((c + 1) & 1);             // other parity: chunk c-1 readers done pre-barrier
      if (c + 2 < 10) ISSUE(c + 2);
      __syncthreads();                // chunk c+1 visible
    }
  }

  // ---- butterfly argmin across the 16 lanes (columns) of each g-group ----
  #pragma unroll
  for (int off = 8; off >= 1; off >>= 1) {
    #pragma unroll
    for (int r = 0; r < 4; ++r) {
      const float ov = __shfl_xor(bv[r], off);
      const int   oi = __shfl_xor(bix[r], off);
      if (ov < bv[r] || (ov == bv[r] && oi < bix[r])) { bv[r] = ov; bix[r] = oi; }
    }
  }
  if (c15 == 0) {
    #pragma unroll
    for (int r = 0; r < 4; ++r) {
      const int row = wv * 16 + g * 4 + r;     // local row 0..127
      bsel[row] = bix[r];
      out[(size_t)NROW * D + row0 + row] = (float)bix[r];
    }
  }
  __syncthreads();

  // ---- gather chosen codes (exact f32 copy), 4 threads per row ----
  {
    const int lr = t >> 2;            // 0..127
    const int q = t & 3;
    const int code = bsel[lr];
    const float* cp = cb + (size_t)code * D;
    float* op = out + (size_t)(row0 + lr) * D;
    #pragma unroll
    for (int e = 0; e < 16; ++e) {
      *(float4*)(op + e * 16 + q * 4) = *(const float4*)(cp + e * 16 + q * 4);
    }
  }
#undef ISSUE
#undef WRITE
}

extern "C" void kernel_launch(void* const* d_in, const int* in_sizes, int n_in,
                              void* d_out, int out_size, void* d_ws, size_t ws_size,
                              hipStream_t stream) {
  const float* x    = (const float*)d_in[0];
  const float* w    = (const float*)d_in[1];
  const float* bias = (const float*)d_in[2];
  const float* cb   = (const float*)d_in[3];
  float* out = (float*)d_out;

  unsigned long long* acc = (unsigned long long*)d_ws;
  float* meanb = (float*)((char*)d_ws + 4096);
  float* rsb   = meanb + 256;
  float* cnorm = rsb + 256;
  _Float16* cbx = (_Float16*)((char*)d_ws + 8192);   // 320 KB

  k_zero<<<1, 256, 0, stream>>>(acc);
  k_cbprep<<<dim3(20, 8), 64, 0, stream>>>(cb, cbx);
  k_stats_partial<<<512, 256, 0, stream>>>(x, acc);
  k_stats_final<<<2, 256, 0, stream>>>(acc, cb, meanb, rsb, cnorm);
  k_main<<<NROW / 128, 512, 0, stream>>>(x, w, bias, cb, meanb, rsb, cnorm, cbx, out);
}